// Round 4
// baseline (664.374 us; speedup 1.0000x reference)
//
#include <hip/hip_runtime.h>
#include <math.h>

#define BB 4096
#define CC 32
#define TT 512
#define NOUTC 16
#define EPSF 1e-5f
#define XS 520    // bf16 [c][t] row stride in shorts
#define XST 40    // bf16 [t][c] row stride in shorts (16B-aligned rows)

// ws layout (floats):
// 0..31 scale1 | 32..63 shift1 | 64..95 scale2 | 96..127 shift2
// 128..1183: Gred (G1[1024] + s1[32])
// 2048: hT[32][4096] (131072)
// 133120: part[4096][1056] (4325376)  -> ~17.8 MB total

typedef __attribute__((ext_vector_type(16))) float f32x16;
typedef __attribute__((ext_vector_type(4)))  float f32x4;
typedef __attribute__((ext_vector_type(8)))  short short8;
typedef __attribute__((ext_vector_type(4)))  unsigned int u32x4;
typedef __attribute__((ext_vector_type(2)))  unsigned int u32x2;
typedef __attribute__((ext_vector_type(4)))  float vf4;
typedef vf4 __attribute__((aligned(4))) vf4u;

__device__ __forceinline__ unsigned short f2b(float f) {
  unsigned int u = __builtin_bit_cast(unsigned int, f);
  return (unsigned short)((u + 0x7FFFu + ((u >> 16) & 1u)) >> 16);
}
__device__ __forceinline__ float b2f(unsigned short h) {
  return __builtin_bit_cast(float, ((unsigned int)h) << 16);
}
__device__ __forceinline__ float blo(unsigned int u) {
  return __builtin_bit_cast(float, u << 16);
}
__device__ __forceinline__ float bhi(unsigned int u) {
  return __builtin_bit_cast(float, u & 0xFFFF0000u);
}

// depthwise conv, one channel, two t-columns (t0=2*tid, t0+1)
__device__ __forceinline__ void conv1(const float* __restrict__ deb,
    const float* __restrict__ dw, const float* __restrict__ db_,
    int c, int off, int tid, float& A, float& Bv) {
  vf4u v = *reinterpret_cast<const vf4u*>(deb + c * TT + off);
  float vm1 = (tid == 0) ? 0.f : ((tid == 255) ? v.y : v.x);
  float v0  = (tid == 0) ? v.x : ((tid == 255) ? v.z : v.y);
  float vp1 = (tid == 0) ? v.y : ((tid == 255) ? v.w : v.z);
  float vp2 = (tid == 0) ? v.z : ((tid == 255) ? 0.f : v.w);
  float w0 = dw[c * 3], w1 = dw[c * 3 + 1], w2 = dw[c * 3 + 2], bc = db_[c];
  A  = fmaf(w0, vm1, fmaf(w1, v0, fmaf(w2, vp1, bc)));
  Bv = fmaf(w0, v0, fmaf(w1, vp1, fmaf(w2, vp2, bc)));
}

// ---------------- kernel A: depthwise -> bf16 x1 Gram + sum partials ----------------
__global__ __launch_bounds__(256) void kA_gram(const float* __restrict__ de,
    const float* __restrict__ dw, const float* __restrict__ db_,
    float* __restrict__ part) {
  __shared__ __align__(16) unsigned short x_s[CC * XS];   // 33280 B
  __shared__ float gramP[4][CC * CC];                     // 16384 B
  __shared__ float red16[CC * 8];                         // 1024 B
  int tid = threadIdx.x, b = blockIdx.x;
  int w = tid >> 6, lane = tid & 63;
  const float* deb = de + (size_t)b * CC * TT;
  int t0 = tid * 2;
  int off = (tid == 0) ? 0 : ((tid == 255) ? t0 - 2 : t0 - 1);
  for (int c = 0; c < CC; c++) {
    float a, bv;
    conv1(deb, dw, db_, c, off, tid, a, bv);
    *(unsigned int*)(&x_s[c * XS + t0]) = (unsigned int)f2b(a) | ((unsigned int)f2b(bv) << 16);
  }
  __syncthreads();
  // s1 partials (sum over t of bf16 x1)
  {
    int c = tid >> 3, j = tid & 7;
    float s = 0.f;
#pragma unroll
    for (int it = 0; it < 8; it++) {
      u32x4 u = *reinterpret_cast<const u32x4*>(&x_s[c * XS + j * 64 + it * 8]);
#pragma unroll
      for (int k = 0; k < 4; k++) s += blo(u[k]) + bhi(u[k]);
    }
    red16[c * 8 + j] = s;
  }
  // Gram of x1: 4 waves, K split 4 x 128, A-frag == B-frag
  {
    int m = lane & 31, kh = lane >> 5;
    f32x16 acc;
#pragma unroll
    for (int r = 0; r < 16; r++) acc[r] = 0.f;
    int kbase = w * 128 + kh * 8;
#pragma unroll
    for (int kk = 0; kk < 128; kk += 16) {
      short8 a = *(const short8*)(&x_s[m * XS + kbase + kk]);
      acc = __builtin_amdgcn_mfma_f32_32x32x16_bf16(a, a, acc, 0, 0, 0);
    }
#pragma unroll
    for (int r = 0; r < 16; r++) {
      int row = (r & 3) + 8 * (r >> 2) + 4 * kh;
      gramP[w][row * CC + m] = acc[r];
    }
  }
  __syncthreads();
  float* pb = part + (size_t)b * 1056;
  for (int i = tid; i < CC * CC; i += 256)
    pb[i] = gramP[0][i] + gramP[1][i] + gramP[2][i] + gramP[3][i];
  if (tid < CC) {
    float s = 0.f;
#pragma unroll
    for (int j = 0; j < 8; j++) s += red16[tid * 8 + j];
    pb[1024 + tid] = s;
  }
}

// ---------------- kernel 2r: reduce partials over the batch ----------------
__global__ __launch_bounds__(256) void k2_reduce(const float* __restrict__ part,
                                                 float* __restrict__ Gred) {
  __shared__ float red[8][32];
  int tid = threadIdx.x;
  int j = blockIdx.x * 32 + (tid & 31);
  int sub = tid >> 5;
  float s = 0.f;
  if (j < 1056) {
    for (int bb = sub; bb < BB; bb += 8) s += part[(size_t)bb * 1056 + j];
  }
  red[sub][tid & 31] = s;
  __syncthreads();
  if (tid < 32 && blockIdx.x * 32 + tid < 1056) {
    float t = 0.f;
#pragma unroll
    for (int k = 0; k < 8; k++) t += red[k][tid];
    Gred[blockIdx.x * 32 + tid] = t;
  }
}

// ---------------- kernel 2s: BN1 scale/shift from G1, s1 ----------------
__global__ void k2_stats(const float* __restrict__ Gred,
                         const float* __restrict__ pw, const float* __restrict__ pwb,
                         const float* __restrict__ g, const float* __restrict__ bta,
                         float* __restrict__ ws) {
  int o = threadIdx.x;
  if (o >= CC) return;
  const float* G1 = Gred;
  const float* s1 = Gred + 1024;
  float N = (float)BB * (float)TT;
  float spo = 0.f;
  for (int c = 0; c < CC; c++) spo = fmaf(pw[o * CC + c], s1[c], spo);
  float mean = spo / N + pwb[o];
  float q = 0.f;
  for (int c = 0; c < CC; c++) {
    float t = 0.f;
    for (int c2 = 0; c2 < CC; c2++) t = fmaf(G1[c * CC + c2], pw[o * CC + c2], t);
    q = fmaf(pw[o * CC + c], t, q);
  }
  float msq = q / N + 2.f * pwb[o] * (spo / N) + pwb[o] * pwb[o];
  float var = msq - mean * mean;
  float sc = g[o] / sqrtf(var + EPSF);
  ws[o] = sc;
  ws[32 + o] = bta[o] - mean * sc;
}

// ---------------- kernel C: per-sample main pipeline ----------------
__global__ __launch_bounds__(256) void kC_main(const float* __restrict__ de,
    const float* __restrict__ dw, const float* __restrict__ db_,
    const float* __restrict__ pw, const float* __restrict__ ws,
    const float* __restrict__ gcw, const float* __restrict__ fcw,
    const float* __restrict__ fcb, float* __restrict__ hT,
    const float* __restrict__ pwb) {
  __shared__ __align__(16) unsigned short bufA[TT * XST];   // 40960 B: x1T, then x_s, then epilogue bufs
  __shared__ __align__(16) unsigned short gc_s[NOUTC * XS]; // 16640 B
  __shared__ __align__(16) unsigned short pwh_s[CC * CC];   // 2048 B
  __shared__ __align__(16) unsigned short pwl_s[CC * CC];   // 2048 B
  __shared__ float sc_s[CC], sh_s[CC];
  __shared__ float gramP[2][CC * CC];                       // 8192 B
  __shared__ float zP[2][CC * NOUTC];                       // 4096 B
  __shared__ float num_s[CC * 33];                          // 4224 B
  __shared__ float red16[CC * 8];                           // 1024 B
  __shared__ float mu_s[CC], inv_s[CC];

  int tid = threadIdx.x;
  int b = BB - 1 - blockIdx.x;    // reversed for L3 tail reuse after kA
  int w = tid >> 6, lane = tid & 63;
  const float* deb = de + (size_t)b * CC * TT;

  // stage gc_w^T, pw hi/lo, BN1 scale/shift (pwb folded into shift)
  for (int i = tid; i < TT * NOUTC; i += 256) {
    int t = i >> 4, o = i & 15;
    gc_s[o * XS + t] = f2b(gcw[i]);
  }
  for (int i = tid; i < CC * CC; i += 256) {
    float p = pw[i];
    unsigned short h = f2b(p);
    pwh_s[i] = h;
    pwl_s[i] = f2b(p - b2f(h));
  }
  if (tid < CC) {
    float sc = ws[tid];
    sc_s[tid] = sc;
    sh_s[tid] = fmaf(sc, pwb[tid], ws[32 + tid]);   // fold pwb: BN(mfma_acc + pwb)
  }

  // depthwise conv -> bf16 x1T [t][c]
  {
    int t0 = tid * 2;
    int off = (tid == 0) ? 0 : ((tid == 255) ? t0 - 2 : t0 - 1);
#pragma unroll
    for (int cc = 0; cc < 4; cc++) {
      unsigned int pa[4], pb[4];
#pragma unroll
      for (int k = 0; k < 8; k += 2) {
        float a0, b0, a1, b1;
        conv1(deb, dw, db_, cc * 8 + k, off, tid, a0, b0);
        conv1(deb, dw, db_, cc * 8 + k + 1, off, tid, a1, b1);
        pa[k >> 1] = (unsigned int)f2b(a0) | ((unsigned int)f2b(a1) << 16);
        pb[k >> 1] = (unsigned int)f2b(b0) | ((unsigned int)f2b(b1) << 16);
      }
      u32x2 wa0 = {pa[0], pa[1]}, wa1 = {pa[2], pa[3]};
      u32x2 wb0 = {pb[0], pb[1]}, wb1 = {pb[2], pb[3]};
      *(u32x2*)(&bufA[(size_t)t0 * XST + cc * 8]) = wa0;
      *(u32x2*)(&bufA[(size_t)t0 * XST + cc * 8 + 4]) = wa1;
      *(u32x2*)(&bufA[(size_t)(t0 + 1) * XST + cc * 8]) = wb0;
      *(u32x2*)(&bufA[(size_t)(t0 + 1) * XST + cc * 8 + 4]) = wb1;
    }
  }
  __syncthreads();

  // pointwise via MFMA 16x16x32: A = pw (hi+lo bf16), B = x1T. 64 tiles = 2 o-halves x 32 t-tiles.
  int n16 = lane & 15, q = lane >> 4;
  int h = w >> 1, ct0 = (w & 1) * 16;
  f32x4 acc[16];
#pragma unroll
  for (int i = 0; i < 16; i++) { acc[i][0] = 0.f; acc[i][1] = 0.f; acc[i][2] = 0.f; acc[i][3] = 0.f; }
  {
    short8 ahi = *(const short8*)(&pwh_s[(h * 16 + n16) * CC + q * 8]);
    short8 alo = *(const short8*)(&pwl_s[(h * 16 + n16) * CC + q * 8]);
#pragma unroll
    for (int i = 0; i < 16; i++) {
      int t = (ct0 + i) * 16 + n16;
      short8 bx = *(const short8*)(&bufA[(size_t)t * XST + q * 8]);
      acc[i] = __builtin_amdgcn_mfma_f32_16x16x32_bf16(alo, bx, acc[i], 0, 0, 0);
      acc[i] = __builtin_amdgcn_mfma_f32_16x16x32_bf16(ahi, bx, acc[i], 0, 0, 0);
    }
  }
  float scr[4], shr[4];
#pragma unroll
  for (int r = 0; r < 4; r++) {
    int o = h * 16 + q * 4 + r;
    scr[r] = sc_s[o]; shr[r] = sh_s[o];
  }
  __syncthreads();   // all x1T reads done; bufA can be overwritten as x_s

  // BN1 + relu + round -> x_s [c][t] (bufA reinterpreted, stride XS)
  unsigned short* xsv = bufA;
#pragma unroll
  for (int i = 0; i < 16; i++) {
    int t = (ct0 + i) * 16 + n16;
#pragma unroll
    for (int r = 0; r < 4; r++) {
      int o = h * 16 + q * 4 + r;
      float val = fmaxf(fmaf(acc[i][r], scr[r], shr[r]), 0.f);
      xsv[o * XS + t] = f2b(val);
    }
  }
  __syncthreads();

  // mu partials from x_s
  {
    int c = tid >> 3, j = tid & 7;
    float s = 0.f;
#pragma unroll
    for (int it = 0; it < 8; it++) {
      u32x4 u = *reinterpret_cast<const u32x4*>(&xsv[c * XS + j * 64 + it * 8]);
#pragma unroll
      for (int k = 0; k < 4; k++) s += blo(u[k]) + bhi(u[k]);
    }
    red16[c * 8 + j] = s;
  }
  // Gram (waves 0,1) and Z (waves 2,3)
  if (w < 2) {
    int m = lane & 31, kh = lane >> 5;
    f32x16 g16;
#pragma unroll
    for (int r = 0; r < 16; r++) g16[r] = 0.f;
    int kbase = w * 256 + kh * 8;
#pragma unroll
    for (int kk = 0; kk < 256; kk += 16) {
      short8 a = *(const short8*)(&xsv[m * XS + kbase + kk]);
      g16 = __builtin_amdgcn_mfma_f32_32x32x16_bf16(a, a, g16, 0, 0, 0);
    }
#pragma unroll
    for (int r = 0; r < 16; r++) {
      int row = (r & 3) + 8 * (r >> 2) + 4 * kh;
      gramP[w][row * CC + m] = g16[r];
    }
  } else {
    int w2 = w - 2;
    f32x4 ac0, ac1;
#pragma unroll
    for (int r = 0; r < 4; r++) { ac0[r] = 0.f; ac1[r] = 0.f; }
    int kbase = w2 * 256 + q * 8;
#pragma unroll
    for (int kk = 0; kk < 256; kk += 32) {
      short8 bfr = *(const short8*)(&gc_s[n16 * XS + kbase + kk]);
      short8 af0 = *(const short8*)(&xsv[n16 * XS + kbase + kk]);
      short8 af1 = *(const short8*)(&xsv[(16 + n16) * XS + kbase + kk]);
      ac0 = __builtin_amdgcn_mfma_f32_16x16x32_bf16(af0, bfr, ac0, 0, 0, 0);
      ac1 = __builtin_amdgcn_mfma_f32_16x16x32_bf16(af1, bfr, ac1, 0, 0, 0);
    }
#pragma unroll
    for (int r = 0; r < 4; r++) {
      int row = q * 4 + r;
      zP[w2][row * NOUTC + n16] = ac0[r];
      zP[w2][(16 + row) * NOUTC + n16] = ac1[r];
    }
  }
  __syncthreads();
  // epilogue buffers alias bufA (x_s dead)
  float* Zi_s = (float*)bufA;
  float* g2_s = Zi_s + 512;
  float* red2 = Zi_s + 1024;   // 288 floats
  if (tid < CC) {
    float s = 0.f;
#pragma unroll
    for (int j = 0; j < 8; j++) s += red16[tid * 8 + j];
    mu_s[tid] = s;
  }
  __syncthreads();
  for (int i = tid; i < CC * CC; i += 256) {
    int n = i >> 5, m = i & 31;
    num_s[n * 33 + m] = gramP[0][i] + gramP[1][i] - mu_s[n] * mu_s[m] * (1.f / (float)TT);
  }
  for (int i = tid; i < CC * NOUTC; i += 256) Zi_s[i] = zP[0][i] + zP[1][i];
  __syncthreads();
  if (tid < CC) inv_s[tid] = rsqrtf(num_s[tid * 33 + tid]);
  __syncthreads();
  for (int i = tid; i < CC * NOUTC; i += 256) {
    int n = i >> 4, o = i & 15;
    float s = 0.f;
#pragma unroll
    for (int m = 0; m < CC; m++) s = fmaf(num_s[n * 33 + m] * inv_s[m], Zi_s[m * NOUTC + o], s);
    g2_s[i] = fmaxf(s * inv_s[n], 0.f);
  }
  __syncthreads();
  {
    int j = tid & 31, ch = tid >> 5;
    float p = 0.f;
#pragma unroll
    for (int ii = 0; ii < 64; ii++) {
      int i = ch * 64 + ii;
      p = fmaf(g2_s[i], fcw[i * CC + j], p);
    }
    red2[j * 9 + ch] = p;
  }
  __syncthreads();
  if (tid < CC) {
    float hh = fcb[tid];
#pragma unroll
    for (int ch = 0; ch < 8; ch++) hh += red2[tid * 9 + ch];
    hT[(size_t)tid * BB + b] = hh;
  }
}

// ---------------- kernel 4: BN2 stats ----------------
__global__ void k4_bn2(const float* __restrict__ hT, const float* __restrict__ g,
                       const float* __restrict__ bta, float* __restrict__ ws) {
  __shared__ float redS[256], redQ[256];
  int j = blockIdx.x, tid = threadIdx.x;
  const float* row = hT + (size_t)j * BB;
  float s = 0, qq = 0;
  for (int i = tid; i < BB; i += 256) { float v = row[i]; s += v; qq = fmaf(v, v, qq); }
  redS[tid] = s; redQ[tid] = qq;
  __syncthreads();
  for (int k = 128; k > 0; k >>= 1) {
    if (tid < k) { redS[tid] += redS[tid + k]; redQ[tid] += redQ[tid + k]; }
    __syncthreads();
  }
  if (tid == 0) {
    float N = (float)BB;
    float mean = redS[0] / N;
    float var = redQ[0] / N - mean * mean;
    float sc = g[j] / sqrtf(var + EPSF);
    ws[64 + j] = sc;
    ws[96 + j] = bta[j] - mean * sc;
  }
}

// ---------------- kernel 5: BN2 apply + sigmoid + classifier ----------------
__global__ void k5_out(const float* __restrict__ hT, const float* __restrict__ ws,
                       const float* __restrict__ clsw, const float* __restrict__ clsb,
                       float* __restrict__ out) {
  __shared__ float hs[CC * 257];
  int b0 = blockIdx.x * 256, tid = threadIdx.x;
  for (int i = tid; i < CC * 256; i += 256) {
    int j = i >> 8, bb = i & 255;
    float v = fmaf(hT[(size_t)j * BB + b0 + bb], ws[64 + j], ws[96 + j]);
    hs[j * 257 + bb] = 1.f / (1.f + expf(-v));
  }
  __syncthreads();
  float o0 = clsb[0], o1 = clsb[1], o2 = clsb[2], o3 = clsb[3];
#pragma unroll
  for (int j = 0; j < CC; j++) {
    float hv = hs[j * 257 + tid];
    o0 = fmaf(hv, clsw[j * 4 + 0], o0);
    o1 = fmaf(hv, clsw[j * 4 + 1], o1);
    o2 = fmaf(hv, clsw[j * 4 + 2], o2);
    o3 = fmaf(hv, clsw[j * 4 + 3], o3);
  }
  float4* out4 = reinterpret_cast<float4*>(out);
  out4[b0 + tid] = make_float4(o0, o1, o2, o3);
}

extern "C" void kernel_launch(void* const* d_in, const int* in_sizes, int n_in,
                              void* d_out, int out_size, void* d_ws, size_t ws_size,
                              hipStream_t stream) {
  const float* de   = (const float*)d_in[0];
  const float* dw   = (const float*)d_in[2];
  const float* db_  = (const float*)d_in[3];
  const float* pw   = (const float*)d_in[4];
  const float* pwb  = (const float*)d_in[5];
  const float* bn1g = (const float*)d_in[6];
  const float* bn1b = (const float*)d_in[7];
  const float* gcw  = (const float*)d_in[8];
  const float* fcw  = (const float*)d_in[9];
  const float* fcb  = (const float*)d_in[10];
  const float* bn2g = (const float*)d_in[11];
  const float* bn2b = (const float*)d_in[12];
  const float* clsw = (const float*)d_in[13];
  const float* clsb = (const float*)d_in[14];

  float* ws   = (float*)d_ws;
  float* Gred = ws + 128;
  float* hT   = ws + 2048;
  float* part = ws + 133120;
  float* out  = (float*)d_out;

  kA_gram<<<BB, 256, 0, stream>>>(de, dw, db_, part);
  k2_reduce<<<33, 256, 0, stream>>>(part, Gred);
  k2_stats<<<1, 64, 0, stream>>>(Gred, pw, pwb, bn1g, bn1b, ws);
  kC_main<<<BB, 256, 0, stream>>>(de, dw, db_, pw, ws, gcw, fcw, fcb, hT, pwb);
  k4_bn2<<<CC, 256, 0, stream>>>(hT, bn2g, bn2b, ws);
  k5_out<<<BB / 256, 256, 0, stream>>>(hT, ws, clsw, clsb, out);
}